// Round 3
// baseline (146.209 us; speedup 1.0000x reference)
//
#include <hip/hip_runtime.h>
#include <hip/hip_bf16.h>
#include <math.h>

typedef __attribute__((ext_vector_type(8))) short bf16x8;
typedef __attribute__((ext_vector_type(16))) float f32x16;

#define B_ 2
#define L_ 2048
#define S_ 2048
#define H_ 16
#define E_ 64
#define D_ 64

#if __has_builtin(__builtin_amdgcn_exp2f)
#define EXP2(x) __builtin_amdgcn_exp2f(x)
#else
#define EXP2(x) exp2f(x)
#endif

__device__ __forceinline__ unsigned pkbf(float a, float b) {
  __hip_bfloat162 h = __float22bfloat162_rn(float2{a, b});
  return *(unsigned*)&h;
}

// D-frag row for mfma_f32_32x32x16: row = (r&3) + 8*(r>>2) + 4*hi5
__device__ __forceinline__ int crow(int r, int hi5) {
  return (r & 3) + ((r >> 2) << 3) + (hi5 << 2);
}

__global__ __launch_bounds__(128, 2)
void fa_fwd2(const float* __restrict__ Qp, const float* __restrict__ Kp,
             const float* __restrict__ Vp, float* __restrict__ Op) {
  __shared__ uint4 sK[512];   // K tile: 64 kv x 64 e, bf16, 128B rows, XOR-swizzled
  __shared__ uint4 sV[512];   // V^T tile: 64 d x 64 kv, bf16, 128B rows, XOR-swizzled
  char* lk = (char*)sK;
  char* lv = (char*)sV;

  const int tid  = threadIdx.x;
  const int lane = tid & 63;
  const int w    = tid >> 6;      // 2 waves
  const int l31  = lane & 31;
  const int hi5  = lane >> 5;

  // XCD-chunked swizzle (512 % 8 == 0, bijective) + heavy-diagonal-first
  const int swz = ((blockIdx.x & 7) << 6) | (blockIdx.x >> 3);
  const int bh  = swz >> 4;                 // 4 (b,h) pairs per XCD chunk
  const int b   = bh >> 4, h = bh & 15;
  const int q0  = (15 - (swz & 15)) << 7;   // 128-row q block, heavy first
  const int nt  = (q0 >> 6) + 2;            // kv tiles of 64

  const float cs = 0.125f * 1.44269504088896f;  // 1/sqrt(E) * log2(e)

  // ---- Q fragments (B-operand of swapped QK^T), pre-scaled, in regs ----
  bf16x8 qf[2][4];
  #pragma unroll
  for (int qt = 0; qt < 2; ++qt) {
    const int qg = q0 + w * 64 + qt * 32 + l31;
    const float* gq = Qp + ((size_t)(b * L_ + qg) * H_ + h) * E_ + hi5 * 8;
    #pragma unroll
    for (int ec = 0; ec < 4; ++ec) {
      float4 a = *(const float4*)(gq + ec * 16);
      float4 c = *(const float4*)(gq + ec * 16 + 4);
      uint4 u;
      u.x = pkbf(a.x * cs, a.y * cs);
      u.y = pkbf(a.z * cs, a.w * cs);
      u.z = pkbf(c.x * cs, c.y * cs);
      u.w = pkbf(c.z * cs, c.w * cs);
      qf[qt][ec] = *(bf16x8*)&u;
    }
  }

  f32x16 acc[2][2];
  #pragma unroll
  for (int qt = 0; qt < 2; ++qt)
    #pragma unroll
    for (int dt = 0; dt < 2; ++dt)
      #pragma unroll
      for (int r = 0; r < 16; ++r) acc[qt][dt][r] = 0.f;

  float mrun[2] = {-INFINITY, -INFINITY};
  float lsum[2] = {0.f, 0.f};

  for (int t = 0; t < nt; ++t) {
    const int kv0 = t * 64;
    __syncthreads();   // prev tile's LDS reads done before restage

    // ---- stage K: 64 x 64 f32 -> bf16 (rows 128B, ^((row&7)<<4)) ----
    {
      const int row = tid >> 1, sg = tid & 1;
      const float* gp = Kp + ((size_t)(b * S_ + kv0 + row) * H_ + h) * E_ + sg * 32;
      const int base = row * 128 + sg * 64;
      const int sw = (row & 7) << 4;
      #pragma unroll
      for (int j = 0; j < 4; ++j) {
        float4 a = *(const float4*)(gp + j * 8);
        float4 c = *(const float4*)(gp + j * 8 + 4);
        uint4 u;
        u.x = pkbf(a.x, a.y); u.y = pkbf(a.z, a.w);
        u.z = pkbf(c.x, c.y); u.w = pkbf(c.z, c.w);
        *(uint4*)(lk + ((base + j * 16) ^ sw)) = u;
      }
    }
    // ---- stage V^T: row d holds 64 kv (transpose via coalesced scalar loads) ----
    {
      const int d = tid & 63, kg = tid >> 6;
      const float* gp = Vp + ((size_t)(b * S_ + kv0 + kg * 32) * H_ + h) * D_ + d;
      const int base = d * 128 + kg * 64;
      const int sw = (d & 7) << 4;
      #pragma unroll
      for (int j = 0; j < 4; ++j) {
        float v0 = gp[(size_t)(j * 8 + 0) * (H_ * D_)];
        float v1 = gp[(size_t)(j * 8 + 1) * (H_ * D_)];
        float v2 = gp[(size_t)(j * 8 + 2) * (H_ * D_)];
        float v3 = gp[(size_t)(j * 8 + 3) * (H_ * D_)];
        float v4 = gp[(size_t)(j * 8 + 4) * (H_ * D_)];
        float v5 = gp[(size_t)(j * 8 + 5) * (H_ * D_)];
        float v6 = gp[(size_t)(j * 8 + 6) * (H_ * D_)];
        float v7 = gp[(size_t)(j * 8 + 7) * (H_ * D_)];
        uint4 u;
        u.x = pkbf(v0, v1); u.y = pkbf(v2, v3);
        u.z = pkbf(v4, v5); u.w = pkbf(v6, v7);
        *(uint4*)(lv + ((base + j * 16) ^ sw)) = u;
      }
    }
    __syncthreads();

    if (kv0 > q0 + w * 64 + 63) continue;   // wave fully masked; barriers stay matched

    const bool needmask = (kv0 + 63) > (q0 + w * 64);

    // ---- swapped QK^T: st[qt][c] = S^T[kv 32c..][q], K-frag shared across qt ----
    f32x16 st[2][2];
    #pragma unroll
    for (int qt = 0; qt < 2; ++qt)
      #pragma unroll
      for (int c = 0; c < 2; ++c)
        #pragma unroll
        for (int r = 0; r < 16; ++r) st[qt][c][r] = 0.f;
    #pragma unroll
    for (int c = 0; c < 2; ++c) {
      const int row = c * 32 + l31;
      const int sw = (row & 7) << 4;
      #pragma unroll
      for (int ec = 0; ec < 4; ++ec) {
        bf16x8 kf = *(bf16x8*)(lk + ((row * 128 + ec * 32 + hi5 * 16) ^ sw));
        st[0][c] = __builtin_amdgcn_mfma_f32_32x32x16_bf16(kf, qf[0][ec], st[0][c], 0, 0, 0);
        st[1][c] = __builtin_amdgcn_mfma_f32_32x32x16_bf16(kf, qf[1][ec], st[1][c], 0, 0, 0);
      }
    }

    if (needmask) {
      #pragma unroll
      for (int qt = 0; qt < 2; ++qt) {
        const int qg = q0 + w * 64 + qt * 32 + l31;
        #pragma unroll
        for (int c = 0; c < 2; ++c)
          #pragma unroll
          for (int r = 0; r < 16; ++r)
            if (kv0 + c * 32 + crow(r, hi5) > qg) st[qt][c][r] = -1e30f;
      }
    }

    // ---- online softmax, defer-max (THR=8 in log2 domain) ----
    float pm[2];
    #pragma unroll
    for (int qt = 0; qt < 2; ++qt) {
      float m = st[qt][0][0];
      #pragma unroll
      for (int c = 0; c < 2; ++c)
        #pragma unroll
        for (int r = 0; r < 16; ++r) m = fmaxf(m, st[qt][c][r]);
      m = fmaxf(m, __shfl_xor(m, 32));
      pm[qt] = m;
    }
    const int resc = (pm[0] > mrun[0] + 8.f) || (pm[1] > mrun[1] + 8.f);
    if (__any(resc)) {
      #pragma unroll
      for (int qt = 0; qt < 2; ++qt) {
        const float mn = fmaxf(mrun[qt], pm[qt]);
        const float f = EXP2(mrun[qt] - mn);
        mrun[qt] = mn;
        lsum[qt] *= f;
        #pragma unroll
        for (int r = 0; r < 16; ++r) {
          const float fr = __shfl(f, crow(r, hi5));
          acc[qt][0][r] *= fr;
          acc[qt][1][r] *= fr;
        }
      }
    }
    #pragma unroll
    for (int qt = 0; qt < 2; ++qt) {
      float ps = 0.f;
      #pragma unroll
      for (int c = 0; c < 2; ++c)
        #pragma unroll
        for (int r = 0; r < 16; ++r) {
          st[qt][c][r] = EXP2(st[qt][c][r] - mrun[qt]);
          ps += st[qt][c][r];
        }
      ps += __shfl_xor(ps, 32);
      lsum[qt] += ps;
    }

    // ---- P -> PA fragments (pack pairs + lane^32 exchange) ----
    uint4 pa[2][4];
    #pragma unroll
    for (int qt = 0; qt < 2; ++qt) {
      #pragma unroll
      for (int c = 0; c < 2; ++c) {
        unsigned Dw[8];
        #pragma unroll
        for (int j = 0; j < 8; ++j)
          Dw[j] = pkbf(st[qt][c][2 * j], st[qt][c][2 * j + 1]);
        unsigned y0 = __shfl_xor((int)(hi5 ? Dw[0] : Dw[2]), 32);
        unsigned y1 = __shfl_xor((int)(hi5 ? Dw[1] : Dw[3]), 32);
        unsigned y2 = __shfl_xor((int)(hi5 ? Dw[4] : Dw[6]), 32);
        unsigned y3 = __shfl_xor((int)(hi5 ? Dw[5] : Dw[7]), 32);
        uint4 p0, p1;
        if (hi5) {
          p0 = uint4{y0, y1, Dw[2], Dw[3]};
          p1 = uint4{y2, y3, Dw[6], Dw[7]};
        } else {
          p0 = uint4{Dw[0], Dw[1], y0, y1};
          p1 = uint4{Dw[4], Dw[5], y2, y3};
        }
        pa[qt][2 * c]     = p0;
        pa[qt][2 * c + 1] = p1;
      }
    }

    // ---- PV: acc[qt][dt] += P(32q x 16kv) . V(16kv x 32d), V-frag shared across qt ----
    #pragma unroll
    for (int s = 0; s < 4; ++s) {
      #pragma unroll
      for (int dt = 0; dt < 2; ++dt) {
        const int row = dt * 32 + l31;
        bf16x8 vf = *(bf16x8*)(lv + ((row * 128 + s * 32 + hi5 * 16) ^ ((row & 7) << 4)));
        acc[0][dt] = __builtin_amdgcn_mfma_f32_32x32x16_bf16(*(bf16x8*)&pa[0][s], vf, acc[0][dt], 0, 0, 0);
        acc[1][dt] = __builtin_amdgcn_mfma_f32_32x32x16_bf16(*(bf16x8*)&pa[1][s], vf, acc[1][dt], 0, 0, 0);
      }
    }
  }

  // ---- epilogue: O[q][d] = acc / lsum (lsum broadcast via bpermute) ----
  #pragma unroll
  for (int qt = 0; qt < 2; ++qt) {
    const float inv = 1.f / lsum[qt];
    #pragma unroll
    for (int r = 0; r < 16; ++r) {
      const float wr = __shfl(inv, crow(r, hi5));
      const int qg = q0 + w * 64 + qt * 32 + crow(r, hi5);
      float* go = Op + ((size_t)(b * L_ + qg) * H_ + h) * D_ + l31;
      go[0]  = acc[qt][0][r] * wr;
      go[32] = acc[qt][1][r] * wr;
    }
  }
}

extern "C" void kernel_launch(void* const* d_in, const int* in_sizes, int n_in,
                              void* d_out, int out_size, void* d_ws, size_t ws_size,
                              hipStream_t stream) {
  (void)in_sizes; (void)n_in; (void)d_ws; (void)ws_size; (void)out_size;
  const float* Q = (const float*)d_in[0];
  const float* K = (const float*)d_in[1];
  const float* V = (const float*)d_in[2];
  float* O = (float*)d_out;
  fa_fwd2<<<dim3(512), dim3(128), 0, stream>>>(Q, K, V, O);
}

// Round 4
// 73.371 us; speedup vs baseline: 1.9927x; 1.9927x over previous
//
#include <hip/hip_runtime.h>
#include <hip/hip_bf16.h>
#include <math.h>

typedef __attribute__((ext_vector_type(8))) short bf16x8;
typedef __attribute__((ext_vector_type(16))) float f32x16;

#define B_ 2
#define L_ 2048
#define S_ 2048
#define H_ 16
#define E_ 64
#define D_ 64

#if __has_builtin(__builtin_amdgcn_exp2f)
#define EXP2(x) __builtin_amdgcn_exp2f(x)
#else
#define EXP2(x) exp2f(x)
#endif

__device__ __forceinline__ unsigned pkbf(float a, float b) {
  __hip_bfloat162 h = __float22bfloat162_rn(float2{a, b});
  return *(unsigned*)&h;
}

// D-frag row for mfma_f32_32x32x16: row = (r&3) + 8*(r>>2) + 4*hi5
__device__ __forceinline__ int crow(int r, int hi5) {
  return (r & 3) + ((r >> 2) << 3) + (hi5 << 2);
}

__global__ __launch_bounds__(256, 2)
void fa_fwd4(const float* __restrict__ Qp, const float* __restrict__ Kp,
             const float* __restrict__ Vp, float* __restrict__ Op) {
  __shared__ uint4 sK[512];   // K tile: 64 kv x 64 e, bf16, 128B rows, XOR-swizzled
  __shared__ uint4 sV[512];   // V^T tile: 64 d x 64 kv, bf16, 128B rows, XOR-swizzled
  char* lk = (char*)sK;
  char* lv = (char*)sV;

  const int tid  = threadIdx.x;
  const int lane = tid & 63;
  const int w    = tid >> 6;      // 4 waves
  const int l31  = lane & 31;
  const int hi5  = lane >> 5;

  // XCD-chunked bijective swizzle (512 blocks, 8 XCDs) + heavy-diagonal-first
  const int swz = ((blockIdx.x & 7) << 6) | (blockIdx.x >> 3);
  const int bh  = swz >> 4;                 // 4 (b,h) pairs per XCD chunk
  const int b   = bh >> 4, h = bh & 15;
  const int q0  = (15 - (swz & 15)) << 7;   // 128-row q block, heavy first
  const int qw  = q0 + w * 32;              // this wave's 32 q-rows
  const int nt  = (q0 >> 6) + 2;            // kv tiles of 64

  const float cs = 0.125f * 1.44269504088896f;  // 1/sqrt(E) * log2(e)

  // ---- Q fragments (B-operand of swapped QK^T), pre-scaled, in regs ----
  bf16x8 qf[4];
  {
    const int qg = qw + l31;
    const float* gq = Qp + ((size_t)(b * L_ + qg) * H_ + h) * E_ + hi5 * 8;
    #pragma unroll
    for (int ec = 0; ec < 4; ++ec) {
      float4 a = *(const float4*)(gq + ec * 16);
      float4 c = *(const float4*)(gq + ec * 16 + 4);
      uint4 u;
      u.x = pkbf(a.x * cs, a.y * cs);
      u.y = pkbf(a.z * cs, a.w * cs);
      u.z = pkbf(c.x * cs, c.y * cs);
      u.w = pkbf(c.z * cs, c.w * cs);
      qf[ec] = *(bf16x8*)&u;
    }
  }

  f32x16 acc[2];
  #pragma unroll
  for (int dt = 0; dt < 2; ++dt)
    #pragma unroll
    for (int r = 0; r < 16; ++r) acc[dt][r] = 0.f;

  float mrun = -INFINITY;
  float lsum = 0.f;

  for (int t = 0; t < nt; ++t) {
    const int kv0 = t * 64;
    __syncthreads();   // prev tile's LDS reads done before restage

    // ---- stage K: 64 x 64 f32 -> bf16 (rows 128B, ^((row&7)<<4)) ----
    {
      const int row = tid >> 2, sg = tid & 3;
      const float* gp = Kp + ((size_t)(b * S_ + kv0 + row) * H_ + h) * E_ + sg * 8;
      const int base = row * 128 + sg * 16;
      const int sw = (row & 7) << 4;
      #pragma unroll
      for (int j = 0; j < 2; ++j) {
        float4 a = *(const float4*)(gp + j * 32);
        float4 c = *(const float4*)(gp + j * 32 + 4);
        uint4 u;
        u.x = pkbf(a.x, a.y); u.y = pkbf(a.z, a.w);
        u.z = pkbf(c.x, c.y); u.w = pkbf(c.z, c.w);
        *(uint4*)(lk + ((base + j * 64) ^ sw)) = u;
      }
    }
    // ---- stage V^T: row d holds 64 kv (transpose; each load wave-coalesced) ----
    {
      const int d = tid & 63, kg = tid >> 6;
      const int base = d * 128 + kg * 32;
      const int sw = (d & 7) << 4;
      #pragma unroll
      for (int j = 0; j < 2; ++j) {
        const float* gp = Vp + ((size_t)(b * S_ + kv0 + kg * 16 + j * 8) * H_ + h) * D_ + d;
        float v0 = gp[(size_t)0 * (H_ * D_)];
        float v1 = gp[(size_t)1 * (H_ * D_)];
        float v2 = gp[(size_t)2 * (H_ * D_)];
        float v3 = gp[(size_t)3 * (H_ * D_)];
        float v4 = gp[(size_t)4 * (H_ * D_)];
        float v5 = gp[(size_t)5 * (H_ * D_)];
        float v6 = gp[(size_t)6 * (H_ * D_)];
        float v7 = gp[(size_t)7 * (H_ * D_)];
        uint4 u;
        u.x = pkbf(v0, v1); u.y = pkbf(v2, v3);
        u.z = pkbf(v4, v5); u.w = pkbf(v6, v7);
        *(uint4*)(lv + ((base + j * 16) ^ sw)) = u;
      }
    }
    __syncthreads();

    if (kv0 > qw + 31) continue;   // wave fully masked; barriers stay matched

    const bool needmask = (kv0 + 63) > qw;

    // ---- swapped QK^T: st[c] = S^T[kv 32c..][q] ----
    f32x16 st[2];
    #pragma unroll
    for (int c = 0; c < 2; ++c)
      #pragma unroll
      for (int r = 0; r < 16; ++r) st[c][r] = 0.f;
    #pragma unroll
    for (int c = 0; c < 2; ++c) {
      const int row = c * 32 + l31;
      const int sw = (row & 7) << 4;
      #pragma unroll
      for (int ec = 0; ec < 4; ++ec) {
        bf16x8 kf = *(bf16x8*)(lk + ((row * 128 + ec * 32 + hi5 * 16) ^ sw));
        st[c] = __builtin_amdgcn_mfma_f32_32x32x16_bf16(kf, qf[ec], st[c], 0, 0, 0);
      }
    }

    if (needmask) {
      const int qg = qw + l31;
      #pragma unroll
      for (int c = 0; c < 2; ++c)
        #pragma unroll
        for (int r = 0; r < 16; ++r)
          if (kv0 + c * 32 + crow(r, hi5) > qg) st[c][r] = -1e30f;
    }

    // ---- online softmax, defer-max (THR=8 in log2 domain) ----
    float pm = st[0][0];
    #pragma unroll
    for (int c = 0; c < 2; ++c)
      #pragma unroll
      for (int r = 0; r < 16; ++r) pm = fmaxf(pm, st[c][r]);
    pm = fmaxf(pm, __shfl_xor(pm, 32));

    if (__any(pm > mrun + 8.f)) {
      const float mn = fmaxf(mrun, pm);
      const float f = EXP2(mrun - mn);   // exp2(-inf)=0 on first tile
      mrun = mn;
      lsum *= f;
      #pragma unroll
      for (int r = 0; r < 16; ++r) {
        const float fr = __shfl(f, crow(r, hi5));
        acc[0][r] *= fr;
        acc[1][r] *= fr;
      }
    }
    {
      float ps = 0.f;
      #pragma unroll
      for (int c = 0; c < 2; ++c)
        #pragma unroll
        for (int r = 0; r < 16; ++r) {
          st[c][r] = EXP2(st[c][r] - mrun);
          ps += st[c][r];
        }
      ps += __shfl_xor(ps, 32);
      lsum += ps;
    }

    // ---- P -> PA fragments (pack pairs + lane^32 exchange) ----
    uint4 pa[4];
    #pragma unroll
    for (int c = 0; c < 2; ++c) {
      unsigned Dw[8];
      #pragma unroll
      for (int j = 0; j < 8; ++j)
        Dw[j] = pkbf(st[c][2 * j], st[c][2 * j + 1]);
      unsigned y0 = __shfl_xor((int)(hi5 ? Dw[0] : Dw[2]), 32);
      unsigned y1 = __shfl_xor((int)(hi5 ? Dw[1] : Dw[3]), 32);
      unsigned y2 = __shfl_xor((int)(hi5 ? Dw[4] : Dw[6]), 32);
      unsigned y3 = __shfl_xor((int)(hi5 ? Dw[5] : Dw[7]), 32);
      uint4 p0, p1;
      if (hi5) {
        p0 = uint4{y0, y1, Dw[2], Dw[3]};
        p1 = uint4{y2, y3, Dw[6], Dw[7]};
      } else {
        p0 = uint4{Dw[0], Dw[1], y0, y1};
        p1 = uint4{Dw[4], Dw[5], y2, y3};
      }
      pa[2 * c]     = p0;
      pa[2 * c + 1] = p1;
    }

    // ---- PV: acc[dt] += P(32q x 16kv) . V(16kv x 32d) ----
    #pragma unroll
    for (int s = 0; s < 4; ++s) {
      #pragma unroll
      for (int dt = 0; dt < 2; ++dt) {
        const int row = dt * 32 + l31;
        bf16x8 vf = *(bf16x8*)(lv + ((row * 128 + s * 32 + hi5 * 16) ^ ((row & 7) << 4)));
        acc[dt] = __builtin_amdgcn_mfma_f32_32x32x16_bf16(*(bf16x8*)&pa[s], vf, acc[dt], 0, 0, 0);
      }
    }
  }

  // ---- epilogue: O[q][d] = acc / lsum ----
  {
    const float inv = 1.f / lsum;
    #pragma unroll
    for (int r = 0; r < 16; ++r) {
      const float wr = __shfl(inv, crow(r, hi5));
      const int qg = qw + crow(r, hi5);
      float* go = Op + ((size_t)(b * L_ + qg) * H_ + h) * D_ + l31;
      go[0]  = acc[0][r] * wr;
      go[32] = acc[1][r] * wr;
    }
  }
}

extern "C" void kernel_launch(void* const* d_in, const int* in_sizes, int n_in,
                              void* d_out, int out_size, void* d_ws, size_t ws_size,
                              hipStream_t stream) {
  (void)in_sizes; (void)n_in; (void)d_ws; (void)ws_size; (void)out_size;
  const float* Q = (const float*)d_in[0];
  const float* K = (const float*)d_in[1];
  const float* V = (const float*)d_in[2];
  float* O = (float*)d_out;
  fa_fwd4<<<dim3(512), dim3(256), 0, stream>>>(Q, K, V, O);
}

// Round 7
// 55.608 us; speedup vs baseline: 2.6293x; 1.3194x over previous
//
#include <hip/hip_runtime.h>
#include <hip/hip_bf16.h>
#include <math.h>

typedef __attribute__((ext_vector_type(8))) short bf16x8;
typedef __attribute__((ext_vector_type(16))) float f32x16;

#define B_ 2
#define L_ 2048
#define S_ 2048
#define H_ 16
#define E_ 64
#define D_ 64

#if __has_builtin(__builtin_amdgcn_exp2f)
#define EXP2(x) __builtin_amdgcn_exp2f(x)
#else
#define EXP2(x) exp2f(x)
#endif

__device__ __forceinline__ unsigned pkbf(float a, float b) {
  __hip_bfloat162 h = __float22bfloat162_rn(float2{a, b});
  return *(unsigned*)&h;
}

// D-frag row for mfma_f32_32x32x16: row = (r&3) + 8*(r>>2) + 4*hi5
__device__ __forceinline__ int crow(int r, int hi5) {
  return (r & 3) + ((r >> 2) << 3) + (hi5 << 2);
}

__global__ __launch_bounds__(256, 2)
void fa_fwd5(const float* __restrict__ Qp, const float* __restrict__ Kp,
             const float* __restrict__ Vp, float* __restrict__ Op) {
  // double-buffered: [buf][ K tile (8KB) | V^T tile (8KB) ]
  __shared__ uint4 sbuf[2][1024];

  const int tid  = threadIdx.x;
  const int lane = tid & 63;
  const int w    = tid >> 6;      // 4 waves
  const int l31  = lane & 31;
  const int hi5  = lane >> 5;

  // complementary work-pairing: blocks B and B+256 share bh, get qidx pair
  // (8+r, 7-r) -> per-CU pair total = const 34 kv-tiles (if HW round-robins
  // blocks over CUs). Same bh in pair -> shared K/V in L2.
  const int Bx   = blockIdx.x;
  const int r_   = (Bx >> 5) & 7;
  const int bh   = Bx & 31;
  const int b    = bh >> 4, h = bh & 15;
  const int qidx = (Bx >> 8) ? (7 - r_) : (8 + r_);
  const int q0   = qidx << 7;         // 128-row q block
  const int qw   = q0 + w * 32;       // this wave's 32 q-rows
  const int nt   = 2 * qidx + 2;      // kv tiles of 64

  const float cs = 0.125f * 1.44269504088896f;  // 1/sqrt(E) * log2(e)

  // staging coords
  const int krow = tid >> 2, ksg = tid & 3;     // K: 64 rows x 4 segs
  const int vd   = tid & 63, kg  = tid >> 6;    // V: 64 d-cols x 4 kv-groups
  const int kswz = (krow & 7) << 4;
  const int vswz = (vd & 7) << 4;

  // ---- Q fragments (B-operand of swapped QK^T), pre-scaled, in regs ----
  bf16x8 qf[4];
  {
    const int qg = qw + l31;
    const float* gq = Qp + ((size_t)(b * L_ + qg) * H_ + h) * E_ + hi5 * 8;
    #pragma unroll
    for (int ec = 0; ec < 4; ++ec) {
      float4 a = *(const float4*)(gq + ec * 16);
      float4 c = *(const float4*)(gq + ec * 16 + 4);
      uint4 u;
      u.x = pkbf(a.x * cs, a.y * cs);
      u.y = pkbf(a.z * cs, a.w * cs);
      u.z = pkbf(c.x * cs, c.y * cs);
      u.w = pkbf(c.z * cs, c.w * cs);
      qf[ec] = *(bf16x8*)&u;
    }
  }

  f32x16 acc[2];
  #pragma unroll
  for (int dt = 0; dt < 2; ++dt)
    #pragma unroll
    for (int rr = 0; rr < 16; ++rr) acc[dt][rr] = 0.f;

  float mrun = -INFINITY;
  float lsum = 0.f;

  // ---- prologue: stage tile 0 into buf 0 ----
  {
    char* lk = (char*)&sbuf[0][0];
    char* lv = lk + 8192;
    const float* gk = Kp + ((size_t)(b * S_ + krow) * H_ + h) * E_ + ksg * 8;
    #pragma unroll
    for (int j = 0; j < 2; ++j) {
      float4 a = *(const float4*)(gk + j * 32);
      float4 c = *(const float4*)(gk + j * 32 + 4);
      uint4 u;
      u.x = pkbf(a.x, a.y); u.y = pkbf(a.z, a.w);
      u.z = pkbf(c.x, c.y); u.w = pkbf(c.z, c.w);
      *(uint4*)(lk + ((krow * 128 + ksg * 16 + j * 64) ^ kswz)) = u;
    }
    #pragma unroll
    for (int j = 0; j < 2; ++j) {
      const float* gv = Vp + ((size_t)(b * S_ + kg * 16 + j * 8) * H_ + h) * D_ + vd;
      float v0 = gv[(size_t)0 * (H_ * D_)];
      float v1 = gv[(size_t)1 * (H_ * D_)];
      float v2 = gv[(size_t)2 * (H_ * D_)];
      float v3 = gv[(size_t)3 * (H_ * D_)];
      float v4 = gv[(size_t)4 * (H_ * D_)];
      float v5 = gv[(size_t)5 * (H_ * D_)];
      float v6 = gv[(size_t)6 * (H_ * D_)];
      float v7 = gv[(size_t)7 * (H_ * D_)];
      uint4 u;
      u.x = pkbf(v0, v1); u.y = pkbf(v2, v3);
      u.z = pkbf(v4, v5); u.w = pkbf(v6, v7);
      *(uint4*)(lv + ((vd * 128 + kg * 32 + j * 16) ^ vswz)) = u;
    }
  }
  __syncthreads();

  int cur = 0;
  for (int t = 0; t < nt; ++t, cur ^= 1) {
    const int kv0 = t * 64;
    const bool have_next = (t + 1) < nt;

    // ---- issue next-tile global loads EARLY (in flight during compute) ----
    float4 Ka[2], Kc[2];
    float Vv[16];
    if (have_next) {
      const int kvn = kv0 + 64;
      const float* gk = Kp + ((size_t)(b * S_ + kvn + krow) * H_ + h) * E_ + ksg * 8;
      Ka[0] = *(const float4*)(gk);
      Kc[0] = *(const float4*)(gk + 4);
      Ka[1] = *(const float4*)(gk + 32);
      Kc[1] = *(const float4*)(gk + 36);
      #pragma unroll
      for (int j = 0; j < 2; ++j) {
        const float* gv = Vp + ((size_t)(b * S_ + kvn + kg * 16 + j * 8) * H_ + h) * D_ + vd;
        #pragma unroll
        for (int k2 = 0; k2 < 8; ++k2)
          Vv[j * 8 + k2] = gv[(size_t)k2 * (H_ * D_)];
      }
    }

    // ---- compute on buf[cur] (masked waves skip; barriers stay matched) ----
    if (kv0 <= qw + 31) {
      char* lk = (char*)&sbuf[cur][0];
      char* lv = lk + 8192;
      const bool needmask = (kv0 + 63) > qw;

      f32x16 st[2];
      #pragma unroll
      for (int c = 0; c < 2; ++c)
        #pragma unroll
        for (int rr = 0; rr < 16; ++rr) st[c][rr] = 0.f;
      #pragma unroll
      for (int c = 0; c < 2; ++c) {
        const int row = c * 32 + l31;
        const int sw = (row & 7) << 4;
        #pragma unroll
        for (int ec = 0; ec < 4; ++ec) {
          bf16x8 kf = *(bf16x8*)(lk + ((row * 128 + ec * 32 + hi5 * 16) ^ sw));
          st[c] = __builtin_amdgcn_mfma_f32_32x32x16_bf16(kf, qf[ec], st[c], 0, 0, 0);
        }
      }

      if (needmask) {
        const int qg = qw + l31;
        #pragma unroll
        for (int c = 0; c < 2; ++c)
          #pragma unroll
          for (int rr = 0; rr < 16; ++rr)
            if (kv0 + c * 32 + crow(rr, hi5) > qg) st[c][rr] = -1e30f;
      }

      // online softmax, defer-max (THR=8 in log2 domain)
      float pm = st[0][0];
      #pragma unroll
      for (int c = 0; c < 2; ++c)
        #pragma unroll
        for (int rr = 0; rr < 16; ++rr) pm = fmaxf(pm, st[c][rr]);
      pm = fmaxf(pm, __shfl_xor(pm, 32));

      if (__any(pm > mrun + 8.f)) {
        const float mn = fmaxf(mrun, pm);
        const float f = EXP2(mrun - mn);
        mrun = mn;
        lsum *= f;
        #pragma unroll
        for (int rr = 0; rr < 16; ++rr) {
          const float fr = __shfl(f, crow(rr, hi5));
          acc[0][rr] *= fr;
          acc[1][rr] *= fr;
        }
      }
      {
        float ps = 0.f;
        #pragma unroll
        for (int c = 0; c < 2; ++c)
          #pragma unroll
          for (int rr = 0; rr < 16; ++rr) {
            st[c][rr] = EXP2(st[c][rr] - mrun);
            ps += st[c][rr];
          }
        ps += __shfl_xor(ps, 32);
        lsum += ps;
      }

      // P -> PA fragments (pack pairs + lane^32 exchange)
      uint4 pa[4];
      #pragma unroll
      for (int c = 0; c < 2; ++c) {
        unsigned Dw[8];
        #pragma unroll
        for (int j = 0; j < 8; ++j)
          Dw[j] = pkbf(st[c][2 * j], st[c][2 * j + 1]);
        unsigned y0 = __shfl_xor((int)(hi5 ? Dw[0] : Dw[2]), 32);
        unsigned y1 = __shfl_xor((int)(hi5 ? Dw[1] : Dw[3]), 32);
        unsigned y2 = __shfl_xor((int)(hi5 ? Dw[4] : Dw[6]), 32);
        unsigned y3 = __shfl_xor((int)(hi5 ? Dw[5] : Dw[7]), 32);
        uint4 p0, p1;
        if (hi5) {
          p0 = uint4{y0, y1, Dw[2], Dw[3]};
          p1 = uint4{y2, y3, Dw[6], Dw[7]};
        } else {
          p0 = uint4{Dw[0], Dw[1], y0, y1};
          p1 = uint4{Dw[4], Dw[5], y2, y3};
        }
        pa[2 * c]     = p0;
        pa[2 * c + 1] = p1;
      }

      // PV: acc[dt] += P(32q x 16kv) . V(16kv x 32d)
      #pragma unroll
      for (int s = 0; s < 4; ++s) {
        #pragma unroll
        for (int dt = 0; dt < 2; ++dt) {
          const int row = dt * 32 + l31;
          bf16x8 vf = *(bf16x8*)(lv + ((row * 128 + s * 32 + hi5 * 16) ^ ((row & 7) << 4)));
          acc[dt] = __builtin_amdgcn_mfma_f32_32x32x16_bf16(*(bf16x8*)&pa[s], vf, acc[dt], 0, 0, 0);
        }
      }
    }

    // ---- write next tile into the other buffer (after compute) ----
    if (have_next) {
      char* lk = (char*)&sbuf[cur ^ 1][0];
      char* lv = lk + 8192;
      #pragma unroll
      for (int j = 0; j < 2; ++j) {
        uint4 u;
        u.x = pkbf(Ka[j].x, Ka[j].y); u.y = pkbf(Ka[j].z, Ka[j].w);
        u.z = pkbf(Kc[j].x, Kc[j].y); u.w = pkbf(Kc[j].z, Kc[j].w);
        *(uint4*)(lk + ((krow * 128 + ksg * 16 + j * 64) ^ kswz)) = u;
      }
      #pragma unroll
      for (int j = 0; j < 2; ++j) {
        uint4 u;
        u.x = pkbf(Vv[j * 8 + 0], Vv[j * 8 + 1]);
        u.y = pkbf(Vv[j * 8 + 2], Vv[j * 8 + 3]);
        u.z = pkbf(Vv[j * 8 + 4], Vv[j * 8 + 5]);
        u.w = pkbf(Vv[j * 8 + 6], Vv[j * 8 + 7]);
        *(uint4*)(lv + ((vd * 128 + kg * 32 + j * 16) ^ vswz)) = u;
      }
    }
    __syncthreads();
  }

  // ---- epilogue: O[q][d] = acc / lsum ----
  {
    const float inv = 1.f / lsum;
    #pragma unroll
    for (int rr = 0; rr < 16; ++rr) {
      const float wr = __shfl(inv, crow(rr, hi5));
      const int qg = qw + crow(rr, hi5);
      float* go = Op + ((size_t)(b * L_ + qg) * H_ + h) * D_ + l31;
      go[0]  = acc[0][rr] * wr;
      go[32] = acc[1][rr] * wr;
    }
  }
}

extern "C" void kernel_launch(void* const* d_in, const int* in_sizes, int n_in,
                              void* d_out, int out_size, void* d_ws, size_t ws_size,
                              hipStream_t stream) {
  (void)in_sizes; (void)n_in; (void)d_ws; (void)ws_size; (void)out_size;
  const float* Q = (const float*)d_in[0];
  const float* K = (const float*)d_in[1];
  const float* V = (const float*)d_in[2];
  float* O = (float*)d_out;
  fa_fwd5<<<dim3(512), dim3(256), 0, stream>>>(Q, K, V, O);
}